// Round 12
// baseline (123.989 us; speedup 1.0000x reference)
//
#include <hip/hip_runtime.h>
#include <cstddef>

typedef float  f32x4  __attribute__((ext_vector_type(4)));
typedef __bf16 bf16x8 __attribute__((ext_vector_type(8)));
typedef __bf16 bf16x4 __attribute__((ext_vector_type(4)));

#define DEV static __device__ __forceinline__

DEV float sigf(float x){ return 1.f/(1.f+__expf(-x)); }
DEV float tanh_f(float x){
  x = fminf(fmaxf(x, -20.f), 20.f);
  float e = __expf(2.f*x);
  return (e-1.f)/(e+1.f);
}

DEV bf16x8 cvt8(const float4 a, const float4 b){
  bf16x8 r;
  r[0]=(__bf16)a.x; r[1]=(__bf16)a.y; r[2]=(__bf16)a.z; r[3]=(__bf16)a.w;
  r[4]=(__bf16)b.x; r[5]=(__bf16)b.y; r[6]=(__bf16)b.z; r[7]=(__bf16)b.w;
  return r;
}

// opaque register pin: forbids rematerialization/reload of the value
DEV void pin(bf16x8& v){
  f32x4 t = __builtin_bit_cast(f32x4, v);
  asm volatile("" : "+v"(t));
  v = __builtin_bit_cast(bf16x8, t);
}

// ---------------- fragment-layout convert (W_pe only): f32 -> bf16 MFMA tiles ----
// lane l of tile (gt,sub) holds src[gt*16 + (l&15)][sub*32 + (l>>4)*8 .. +8]
__global__ void k_frag(const float* __restrict__ src, __bf16* __restrict__ dst)
{
  const int idx = blockIdx.x*256 + threadIdx.x;
  const int l   = idx & 63;
  const int sub = (idx >> 6) & 15;
  const int gt  = idx >> 10;
  const float* p = src + ((size_t)gt*16 + (l&15))*512 + sub*32 + (l>>4)*8;
  float4 v0 = *(const float4*)p;
  float4 v1 = *(const float4*)(p+4);
  *(bf16x8*)(dst + ((size_t)(gt*16 + sub)*64 + l)*8) = cvt8(v0, v1);
}

// ---------------- ph = h_last @ W_ph^T : (128,256) ----------------
__global__ void k_ph(const float* __restrict__ h0, const float* __restrict__ W_ph,
                     float* __restrict__ ph)
{
  const int b = blockIdx.x, a = threadIdx.x;
  __shared__ float h_s[1024];
  for (int k = a; k < 1024; k += 256) h_s[k] = h0[(size_t)b*1024 + k];
  __syncthreads();
  const float* wr = W_ph + (size_t)a*1024;
  float acc = 0.f;
  for (int k = 0; k < 1024; k += 4){
    float4 w = *(const float4*)(wr + k);
    acc += w.x*h_s[k] + w.y*h_s[k+1] + w.z*h_s[k+2] + w.w*h_s[k+3];
  }
  ph[b*256 + a] = acc;
}

// ---------------- xh[:,0:512]=embed, xh[:,1024:2048]=h0 ----------------
__global__ void k_concat(const float* __restrict__ embed, const float* __restrict__ h0,
                         float* __restrict__ xh)
{
  const int b = blockIdx.x, tid = threadIdx.x;
  *(float2*)(xh + (size_t)b*2048 + tid*2) = *(const float2*)(embed + (size_t)b*512 + tid*2);
  *(float4*)(xh + (size_t)b*2048 + 1024 + tid*4) = *(const float4*)(h0 + (size_t)b*1024 + tid*4);
}

// ---------------- fused scores+softmax+ctxt (flash-style, online softmax) --------
// grid (4 t-quarters, 128 b) x 512 threads (8 waves). Per block: 128 t rows (4 tiles).
// enc tile (32 t x 512 K) staged ONCE into LDS bf16 row-major [32][520];
// used by QK (MFMA A-frags) and PV. W_pe frags pinned in VGPRs (128 regs/wave).
#define RMW 520
__global__ __launch_bounds__(512,1) void k_fused(
    const float* __restrict__ enc, const __bf16* __restrict__ wpeX,
    const float* __restrict__ ph, const float* __restrict__ w_fc2,
    const unsigned char* __restrict__ mask,
    float* __restrict__ partC, float* __restrict__ partML)
{
  const int th = blockIdx.x;          // t-quarter
  const int b  = blockIdx.y;
  const int tid = threadIdx.x;
  const int w = tid >> 6, l = tid & 63;
  const int la = l & 15, g = l >> 4;

  __shared__ __align__(16) __bf16 rm[2][32*RMW];
  __shared__ float sred[8][32];
  __shared__ float p_s[32];
  __shared__ float ph_s[256], w2_s[256];
  __shared__ float stM, stL, rsS;

  if (tid < 256){ ph_s[tid] = ph[b*256 + tid]; w2_s[tid] = w_fc2[tid]; }
  if (tid == 0){ stM = -1e30f; stL = 0.f; }

  // W_pe fragments in registers, PINNED: wave w owns a-tiles w*2 / w*2+1.
  bf16x8 Bf0[16], Bf1[16];
  {
    const __bf16* bp0 = wpeX + ((size_t)(w*2    )*16*64 + l)*8;
    const __bf16* bp1 = wpeX + ((size_t)(w*2 + 1)*16*64 + l)*8;
    #pragma unroll
    for (int kt = 0; kt < 16; ++kt){
      Bf0[kt] = *(const bf16x8*)(bp0 + (size_t)kt*512);
      Bf1[kt] = *(const bf16x8*)(bp1 + (size_t)kt*512);
    }
    #pragma unroll
    for (int kt = 0; kt < 16; ++kt){ pin(Bf0[kt]); pin(Bf1[kt]); }
  }

  const int t0 = th*128;
  const int srow = tid >> 7;               // 0..3 (row group)
  const int scol = (tid & 127) * 4;        // 0..508
  const float* gsrc = enc + ((size_t)b*512 + t0 + srow)*512 + scol;

  float4 st[8];
  // prologue: stage tile 0 (rows srow+rr*4, cols scol..scol+3)
  #pragma unroll
  for (int rr = 0; rr < 8; ++rr)
    st[rr] = *(const float4*)(gsrc + (size_t)rr*4*512);
  #pragma unroll
  for (int rr = 0; rr < 8; ++rr){
    float4 v = st[rr];
    bf16x4 bv; bv[0]=(__bf16)v.x; bv[1]=(__bf16)v.y; bv[2]=(__bf16)v.z; bv[3]=(__bf16)v.w;
    *(bf16x4*)&rm[0][(srow + rr*4)*RMW + scol] = bv;
  }
  __syncthreads();

  float cacc = 0.f;

  for (int tile = 0; tile < 4; ++tile){
    const int cur = tile & 1;
    // issue next tile's global loads early (arrive under QK compute)
    if (tile < 3){
      const float* gn = gsrc + (size_t)(tile+1)*32*512;
      #pragma unroll
      for (int rr = 0; rr < 8; ++rr)
        st[rr] = *(const float4*)(gn + (size_t)rr*4*512);
    }
    // QK: pe tile (32t x 32a per wave), K=512
    f32x4 acc00 = {0.f,0.f,0.f,0.f}, acc01 = acc00, acc10 = acc00, acc11 = acc00;
    const __bf16* rb = &rm[cur][0];
    #pragma unroll
    for (int kt = 0; kt < 16; ++kt){
      bf16x8 a0 = *(const bf16x8*)(rb + (la     )*RMW + kt*32 + g*8);
      bf16x8 a1 = *(const bf16x8*)(rb + (16 + la)*RMW + kt*32 + g*8);
      acc00 = __builtin_amdgcn_mfma_f32_16x16x32_bf16(a0, Bf0[kt], acc00, 0,0,0);
      acc01 = __builtin_amdgcn_mfma_f32_16x16x32_bf16(a0, Bf1[kt], acc01, 0,0,0);
      acc10 = __builtin_amdgcn_mfma_f32_16x16x32_bf16(a1, Bf0[kt], acc10, 0,0,0);
      acc11 = __builtin_amdgcn_mfma_f32_16x16x32_bf16(a1, Bf1[kt], acc11, 0,0,0);
    }
    // epilogue: partial score over wave's 32 a-cols; D: row=g*4+r, col=la
    {
      const float phv0 = ph_s[w*32 + la],      w2v0 = w2_s[w*32 + la];
      const float phv1 = ph_s[w*32 + 16 + la], w2v1 = w2_s[w*32 + 16 + la];
      #pragma unroll
      for (int gt = 0; gt < 2; ++gt){
        const f32x4 pa = gt ? acc10 : acc00;
        const f32x4 pb = gt ? acc11 : acc01;
        #pragma unroll
        for (int r = 0; r < 4; ++r){
          float s = tanh_f(pa[r] + phv0)*w2v0 + tanh_f(pb[r] + phv1)*w2v1;
          s += __shfl_xor(s, 1, 16);
          s += __shfl_xor(s, 2, 16);
          s += __shfl_xor(s, 4, 16);
          s += __shfl_xor(s, 8, 16);
          if (la == 0) sred[w][gt*16 + g*4 + r] = s;
        }
      }
    }
    // stage-write next tile (loads already in flight)
    if (tile < 3){
      #pragma unroll
      for (int rr = 0; rr < 8; ++rr){
        float4 v = st[rr];
        bf16x4 bv; bv[0]=(__bf16)v.x; bv[1]=(__bf16)v.y; bv[2]=(__bf16)v.z; bv[3]=(__bf16)v.w;
        *(bf16x4*)&rm[cur^1][(srow + rr*4)*RMW + scol] = bv;
      }
    }
    __syncthreads();
    // softmax state update (one half-wave)
    if (tid < 32){
      const int t = tid;
      float s = sred[0][t]+sred[1][t]+sred[2][t]+sred[3][t]
              + sred[4][t]+sred[5][t]+sred[6][t]+sred[7][t];
      const bool mk = mask[b*512 + t0 + tile*32 + t] != 0;
      if (mk) s = -1e30f;
      float mold = stM;
      float mx = s;
      mx = fmaxf(mx, __shfl_xor(mx, 1, 32));
      mx = fmaxf(mx, __shfl_xor(mx, 2, 32));
      mx = fmaxf(mx, __shfl_xor(mx, 4, 32));
      mx = fmaxf(mx, __shfl_xor(mx, 8, 32));
      mx = fmaxf(mx, __shfl_xor(mx, 16, 32));
      float mnew = fmaxf(mold, mx);
      float p = mk ? 0.f : __expf(s - mnew);
      p_s[t] = p;
      float lt = p;
      lt += __shfl_xor(lt, 1, 32);
      lt += __shfl_xor(lt, 2, 32);
      lt += __shfl_xor(lt, 4, 32);
      lt += __shfl_xor(lt, 8, 32);
      lt += __shfl_xor(lt, 16, 32);
      if (t == 0){
        float rs = __expf(mold - mnew);
        rsS = rs;
        stM = mnew;
        stL = stL*rs + lt;
      }
    }
    __syncthreads();
    // PV: thread owns e = tid; enc tile re-used from LDS
    {
      const float rs = rsS;
      float s0 = 0.f, s1 = 0.f, s2 = 0.f, s3 = 0.f;
      const __bf16* rp = &rm[cur][tid];
      #pragma unroll
      for (int t = 0; t < 32; t += 4){
        s0 += p_s[t  ] * (float)rp[(t  )*RMW];
        s1 += p_s[t+1] * (float)rp[(t+1)*RMW];
        s2 += p_s[t+2] * (float)rp[(t+2)*RMW];
        s3 += p_s[t+3] * (float)rp[(t+3)*RMW];
      }
      cacc = cacc*rs + ((s0+s1)+(s2+s3));
    }
  }

  partC[((size_t)th*128 + b)*512 + tid] = cacc;
  if (tid == 0){
    partML[((size_t)th*128 + b)*2 + 0] = stM;
    partML[((size_t)th*128 + b)*2 + 1] = stL;
  }
}

// ---------------- combine 4 t-quarters -> ctxt -> xh[:,512:1024], hc[:,1024:1536] --
__global__ void k_comb(const float* __restrict__ partC, const float* __restrict__ partML,
                       float* __restrict__ xh, float* __restrict__ hc)
{
  const int b = blockIdx.x, e = threadIdx.x;   // 512 threads
  float M = -1e30f;
  #pragma unroll
  for (int q = 0; q < 4; ++q) M = fmaxf(M, partML[(q*128 + b)*2 + 0]);
  float L = 0.f, v = 0.f;
  #pragma unroll
  for (int q = 0; q < 4; ++q){
    float a = __expf(partML[(q*128 + b)*2 + 0] - M);
    L += partML[(q*128 + b)*2 + 1] * a;
    v += partC[(size_t)(q*128 + b)*512 + e] * a;
  }
  v /= L;
  xh[(size_t)b*2048 + 512 + e] = v;
  hc[(size_t)b*1536 + 1024 + e] = v;
}

// ---------------- partial GEMM: Cpart[kc][128][N] = A[:,koff:koff+Kloc] @ W^T ------
__global__ __launch_bounds__(256,2) void k_gemm_part(
    const float* __restrict__ A, int lda,
    const float* __restrict__ W1, int ldw1,
    const float* __restrict__ W2, int ldw2, int ksplit,
    float* __restrict__ Cpart, int ldc, int Kloc)
{
  const int jt = blockIdx.x * 32;
  const int kc = blockIdx.y;
  const int koff = kc * Kloc;
  const int tid = threadIdx.x;
  const int w = tid >> 6, lane = tid & 63;
  const int la = lane & 15, g = lane >> 4;

  __shared__ __align__(16) __bf16 A_s[128][40];
  __shared__ __align__(16) __bf16 B_s[32][40];

  f32x4 acc[2][2];
  #pragma unroll
  for (int i = 0; i < 2; ++i)
    #pragma unroll
    for (int j = 0; j < 2; ++j) acc[i][j] = (f32x4){0.f,0.f,0.f,0.f};

  const int ar = tid >> 1, ac = (tid & 1) * 16;
  const int br = tid >> 3, bc = (tid & 7) * 4;

  for (int kl = 0; kl < Kloc; kl += 32){
    const int kk = koff + kl;
    {
      const float* p = A + (size_t)ar*lda + kk + ac;
      float4 v0 = *(const float4*)(p);
      float4 v1 = *(const float4*)(p+4);
      float4 v2 = *(const float4*)(p+8);
      float4 v3 = *(const float4*)(p+12);
      *(bf16x8*)&A_s[ar][ac]   = cvt8(v0,v1);
      *(bf16x8*)&A_s[ar][ac+8] = cvt8(v2,v3);
    }
    {
      const float* wp = (kk < ksplit)
          ? (W1 + (size_t)(jt+br)*ldw1 + kk + bc)
          : (W2 + (size_t)(jt+br)*ldw2 + (kk - ksplit) + bc);
      float4 v = *(const float4*)wp;
      bf16x4 bv;
      bv[0]=(__bf16)v.x; bv[1]=(__bf16)v.y; bv[2]=(__bf16)v.z; bv[3]=(__bf16)v.w;
      *(bf16x4*)&B_s[br][bc] = bv;
    }
    __syncthreads();
    bf16x8 a0 = *(const bf16x8*)&A_s[w*32 + la][g*8];
    bf16x8 a1 = *(const bf16x8*)&A_s[w*32 + 16 + la][g*8];
    bf16x8 b0 = *(const bf16x8*)&B_s[la][g*8];
    bf16x8 b1 = *(const bf16x8*)&B_s[16 + la][g*8];
    acc[0][0] = __builtin_amdgcn_mfma_f32_16x16x32_bf16(a0, b0, acc[0][0], 0,0,0);
    acc[0][1] = __builtin_amdgcn_mfma_f32_16x16x32_bf16(a0, b1, acc[0][1], 0,0,0);
    acc[1][0] = __builtin_amdgcn_mfma_f32_16x16x32_bf16(a1, b0, acc[1][0], 0,0,0);
    acc[1][1] = __builtin_amdgcn_mfma_f32_16x16x32_bf16(a1, b1, acc[1][1], 0,0,0);
    __syncthreads();
  }

  float* cp = Cpart + (size_t)kc*128*ldc;
  #pragma unroll
  for (int mfi = 0; mfi < 2; ++mfi)
    #pragma unroll
    for (int nf = 0; nf < 2; ++nf)
      #pragma unroll
      for (int r = 0; r < 4; ++r){
        int m = w*32 + mfi*16 + g*4 + r;
        int j = jt + nf*16 + la;
        cp[(size_t)m*ldc + j] = acc[mfi][nf][r];
      }
}

// ---------------- LSTM finisher: sum 4 partials + biases + pointwise ----------------
__global__ void k_lstm_fin(const float* __restrict__ partG, const float* __restrict__ b_ih,
                           const float* __restrict__ b_hh, const float* __restrict__ c0,
                           float* __restrict__ out, float* __restrict__ hc)
{
  const int idx = blockIdx.x*256 + threadIdx.x;   // 0..131071
  const int b = idx >> 10, h = idx & 1023;
  float gi = b_ih[h]        + b_hh[h];
  float gf = b_ih[1024 + h] + b_hh[1024 + h];
  float gg = b_ih[2048 + h] + b_hh[2048 + h];
  float go = b_ih[3072 + h] + b_hh[3072 + h];
  #pragma unroll
  for (int kc = 0; kc < 4; ++kc){
    const float* gp = partG + ((size_t)kc*128 + b)*4096;
    gi += gp[h]; gf += gp[1024 + h]; gg += gp[2048 + h]; go += gp[3072 + h];
  }
  float c1 = sigf(gf)*c0[idx] + sigf(gi)*tanh_f(gg);
  float h1 = sigf(go)*tanh_f(c1);
  out[131072 + idx] = h1;
  out[262144 + idx] = c1;
  hc[(size_t)b*1536 + h] = h1;
}

// ---------------- proj finisher: sum 4 partials + bias + tanh -> out[:131072] ------
__global__ void k_proj_fin(const float* __restrict__ partP, const float* __restrict__ b_proj,
                           float* __restrict__ out)
{
  const int idx = blockIdx.x*256 + threadIdx.x;   // 0..131071
  const int b = idx >> 10, j = idx & 1023;
  float s = b_proj[j];
  #pragma unroll
  for (int kc = 0; kc < 4; ++kc)
    s += partP[((size_t)kc*128 + b)*1024 + j];
  out[idx] = tanh_f(s);
}

extern "C" void kernel_launch(void* const* d_in, const int* in_sizes, int n_in,
                              void* d_out, int out_size, void* d_ws, size_t ws_size,
                              hipStream_t stream)
{
  const float* embed  = (const float*)d_in[0];
  const float* h0     = (const float*)d_in[1];
  const float* c0     = (const float*)d_in[2];
  const float* enc    = (const float*)d_in[3];
  const float* W_ph   = (const float*)d_in[4];
  const float* W_pe   = (const float*)d_in[5];
  const float* w_fc2  = (const float*)d_in[6];
  const float* W_ih   = (const float*)d_in[7];
  const float* W_hh   = (const float*)d_in[8];
  const float* b_ih   = (const float*)d_in[9];
  const float* b_hh   = (const float*)d_in[10];
  const float* W_proj = (const float*)d_in[11];
  const float* b_proj = (const float*)d_in[12];
  const unsigned char* mask = (const unsigned char*)d_in[13];

  float* ws     = (float*)d_ws;
  float* ph     = ws;                   //   32768
  float* xh     = ws + 32768;           //  262144 (128x2048: [embed|ctxt|h])
  float* hc     = ws + 294912;          //  196608 (128x1536: [h1|ctxt])
  float* partC  = ws + 491520;          //  262144 (4 x 128 x 512)
  float* partML = ws + 753664;          //    1024 (4 x 128 x 2)
  float* partG  = ws + 754688;          // 2097152 (4 x 128 x 4096)
  float* partP  = ws + 2851840;         //  524288 (4 x 128 x 1024)
  __bf16* wpeX  = (__bf16*)(ws + 3376128);   // 131072 bf16 (256 KB)
  float* out    = (float*)d_out;

  k_frag  <<<64, 256, 0, stream>>>(W_pe, wpeX);
  k_ph    <<<128, 256, 0, stream>>>(h0, W_ph, ph);
  k_concat<<<128, 256, 0, stream>>>(embed, h0, xh);
  k_fused <<<dim3(4,128), 512, 0, stream>>>(enc, wpeX, ph, w_fc2, mask,
                                            partC, partML);
  k_comb  <<<128, 512, 0, stream>>>(partC, partML, xh, hc);
  k_gemm_part<<<dim3(128,4), 256, 0, stream>>>(xh, 2048, W_ih, 1024, W_hh, 1024, 1024,
                                               partG, 4096, 512);
  k_lstm_fin<<<512, 256, 0, stream>>>(partG, b_ih, b_hh, c0, out, hc);
  k_gemm_part<<<dim3(32,4), 256, 0, stream>>>(hc, 1536, W_proj, 1536, nullptr, 0, 1536,
                                              partP, 1024, 384);
  k_proj_fin<<<512, 256, 0, stream>>>(partP, b_proj, out);
}

// Round 13
// 107.941 us; speedup vs baseline: 1.1487x; 1.1487x over previous
//
#include <hip/hip_runtime.h>
#include <cstddef>

typedef float  f32x4  __attribute__((ext_vector_type(4)));
typedef __bf16 bf16x8 __attribute__((ext_vector_type(8)));
typedef __bf16 bf16x4 __attribute__((ext_vector_type(4)));

#define DEV static __device__ __forceinline__

DEV float sigf(float x){ return 1.f/(1.f+__expf(-x)); }
DEV float tanh_f(float x){
  x = fminf(fmaxf(x, -20.f), 20.f);
  float e = __expf(2.f*x);
  return (e-1.f)/(e+1.f);
}

DEV bf16x8 cvt8(const float4 a, const float4 b){
  bf16x8 r;
  r[0]=(__bf16)a.x; r[1]=(__bf16)a.y; r[2]=(__bf16)a.z; r[3]=(__bf16)a.w;
  r[4]=(__bf16)b.x; r[5]=(__bf16)b.y; r[6]=(__bf16)b.z; r[7]=(__bf16)b.w;
  return r;
}

// opaque register pin: forbids rematerialization/reload of the value
DEV void pin(bf16x8& v){
  f32x4 t = __builtin_bit_cast(f32x4, v);
  asm volatile("" : "+v"(t));
  v = __builtin_bit_cast(bf16x8, t);
}

// ---------------- merged setup: W_pe frag convert / ph GEMV / xh concat ----------
// blocks 0..63: wpeX; 64..191: ph; 192..319: concat.
__global__ void k_setup(const float* __restrict__ W_pe, __bf16* __restrict__ wpeX,
                        const float* __restrict__ h0, const float* __restrict__ W_ph,
                        float* __restrict__ ph, const float* __restrict__ embed,
                        float* __restrict__ xh)
{
  const int bid = blockIdx.x, tid = threadIdx.x;
  __shared__ float h_s[1024];
  if (bid < 64){
    const int idx = bid*256 + tid;
    const int l = idx & 63, sub = (idx >> 6) & 15, gt = idx >> 10;
    const float* p = W_pe + ((size_t)gt*16 + (l&15))*512 + sub*32 + (l>>4)*8;
    float4 v0 = *(const float4*)p;
    float4 v1 = *(const float4*)(p+4);
    *(bf16x8*)(wpeX + ((size_t)(gt*16 + sub)*64 + l)*8) = cvt8(v0, v1);
  } else if (bid < 192){
    const int b = bid - 64;
    for (int k = tid; k < 1024; k += 256) h_s[k] = h0[(size_t)b*1024 + k];
    __syncthreads();
    const float* wr = W_ph + (size_t)tid*1024;
    float acc = 0.f;
    for (int k = 0; k < 1024; k += 4){
      float4 w = *(const float4*)(wr + k);
      acc += w.x*h_s[k] + w.y*h_s[k+1] + w.z*h_s[k+2] + w.w*h_s[k+3];
    }
    ph[b*256 + tid] = acc;
  } else {
    const int b = bid - 192;
    *(float2*)(xh + (size_t)b*2048 + tid*2) = *(const float2*)(embed + (size_t)b*512 + tid*2);
    *(float4*)(xh + (size_t)b*2048 + 1024 + tid*4) = *(const float4*)(h0 + (size_t)b*1024 + tid*4);
  }
}

// ---------------- fused scores+softmax+ctxt (no-max softmax: |s| <= ||w2||_1) ----
// grid (2 t-halves, 128 b) x 512 threads (8 waves). Per block: 256 t rows (8 tiles).
// enc tile (32t x 512K) staged ONCE into LDS bf16 [32][520]; used by QK + PV.
// W_pe frags pinned in VGPRs. p = exp(s) directly (bounded); L accumulated.
#define RMW 520
__global__ __launch_bounds__(512,1) void k_fused(
    const float* __restrict__ enc, const __bf16* __restrict__ wpeX,
    const float* __restrict__ ph, const float* __restrict__ w_fc2,
    const unsigned char* __restrict__ mask,
    float* __restrict__ partC, float* __restrict__ partL)
{
  const int th = blockIdx.x;          // t-half
  const int b  = blockIdx.y;
  const int tid = threadIdx.x;
  const int w = tid >> 6, l = tid & 63;
  const int la = l & 15, g = l >> 4;

  __shared__ __align__(16) __bf16 rm[2][32*RMW];
  __shared__ float sred[8][32];
  __shared__ float p_s[32];
  __shared__ float ph_s[256], w2_s[256];

  if (tid < 256){ ph_s[tid] = ph[b*256 + tid]; w2_s[tid] = w_fc2[tid]; }

  // W_pe fragments in registers, PINNED: wave w owns a-tiles w*2 / w*2+1.
  bf16x8 Bf0[16], Bf1[16];
  {
    const __bf16* bp0 = wpeX + ((size_t)(w*2    )*16*64 + l)*8;
    const __bf16* bp1 = wpeX + ((size_t)(w*2 + 1)*16*64 + l)*8;
    #pragma unroll
    for (int kt = 0; kt < 16; ++kt){
      Bf0[kt] = *(const bf16x8*)(bp0 + (size_t)kt*512);
      Bf1[kt] = *(const bf16x8*)(bp1 + (size_t)kt*512);
    }
    #pragma unroll
    for (int kt = 0; kt < 16; ++kt){ pin(Bf0[kt]); pin(Bf1[kt]); }
  }

  const int t0 = th*256;
  const int srow = tid >> 7;               // 0..3 (row group)
  const int scol = (tid & 127) * 4;        // 0..508
  const float* gsrc = enc + ((size_t)b*512 + t0 + srow)*512 + scol;

  float4 st[8];
  // prologue: stage tile 0
  #pragma unroll
  for (int rr = 0; rr < 8; ++rr)
    st[rr] = *(const float4*)(gsrc + (size_t)rr*4*512);
  #pragma unroll
  for (int rr = 0; rr < 8; ++rr){
    float4 v = st[rr];
    bf16x4 bv; bv[0]=(__bf16)v.x; bv[1]=(__bf16)v.y; bv[2]=(__bf16)v.z; bv[3]=(__bf16)v.w;
    *(bf16x4*)&rm[0][(srow + rr*4)*RMW + scol] = bv;
  }
  __syncthreads();

  float cacc = 0.f;
  float Lacc = 0.f;

  for (int tile = 0; tile < 8; ++tile){
    const int cur = tile & 1;
    // issue next tile's global loads early (arrive under QK compute)
    if (tile < 7){
      const float* gn = gsrc + (size_t)(tile+1)*32*512;
      #pragma unroll
      for (int rr = 0; rr < 8; ++rr)
        st[rr] = *(const float4*)(gn + (size_t)rr*4*512);
    }
    // QK: pe tile (32t x 32a per wave), K=512
    f32x4 acc00 = {0.f,0.f,0.f,0.f}, acc01 = acc00, acc10 = acc00, acc11 = acc00;
    const __bf16* rb = &rm[cur][0];
    #pragma unroll
    for (int kt = 0; kt < 16; ++kt){
      bf16x8 a0 = *(const bf16x8*)(rb + (la     )*RMW + kt*32 + g*8);
      bf16x8 a1 = *(const bf16x8*)(rb + (16 + la)*RMW + kt*32 + g*8);
      acc00 = __builtin_amdgcn_mfma_f32_16x16x32_bf16(a0, Bf0[kt], acc00, 0,0,0);
      acc01 = __builtin_amdgcn_mfma_f32_16x16x32_bf16(a0, Bf1[kt], acc01, 0,0,0);
      acc10 = __builtin_amdgcn_mfma_f32_16x16x32_bf16(a1, Bf0[kt], acc10, 0,0,0);
      acc11 = __builtin_amdgcn_mfma_f32_16x16x32_bf16(a1, Bf1[kt], acc11, 0,0,0);
    }
    // epilogue: partial score over wave's 32 a-cols; D: row=g*4+r, col=la
    {
      const float phv0 = ph_s[w*32 + la],      w2v0 = w2_s[w*32 + la];
      const float phv1 = ph_s[w*32 + 16 + la], w2v1 = w2_s[w*32 + 16 + la];
      #pragma unroll
      for (int gt = 0; gt < 2; ++gt){
        const f32x4 pa = gt ? acc10 : acc00;
        const f32x4 pb = gt ? acc11 : acc01;
        #pragma unroll
        for (int r = 0; r < 4; ++r){
          float s = tanh_f(pa[r] + phv0)*w2v0 + tanh_f(pb[r] + phv1)*w2v1;
          s += __shfl_xor(s, 1, 16);
          s += __shfl_xor(s, 2, 16);
          s += __shfl_xor(s, 4, 16);
          s += __shfl_xor(s, 8, 16);
          if (la == 0) sred[w][gt*16 + g*4 + r] = s;
        }
      }
    }
    // stage-write next tile (loads already in flight; different buffer than PV reads)
    if (tile < 7){
      #pragma unroll
      for (int rr = 0; rr < 8; ++rr){
        float4 v = st[rr];
        bf16x4 bv; bv[0]=(__bf16)v.x; bv[1]=(__bf16)v.y; bv[2]=(__bf16)v.z; bv[3]=(__bf16)v.w;
        *(bf16x4*)&rm[cur^1][(srow + rr*4)*RMW + scol] = bv;
      }
    }
    __syncthreads();               // sred + rm[cur^1] writes visible
    // softmax weights: p = exp(s) directly (no max; |s| bounded by ||w2||_1)
    if (tid < 32){
      const int t = tid;
      float s = sred[0][t]+sred[1][t]+sred[2][t]+sred[3][t]
              + sred[4][t]+sred[5][t]+sred[6][t]+sred[7][t];
      const bool mk = mask[b*512 + t0 + tile*32 + t] != 0;
      float p = mk ? 0.f : __expf(s);
      p_s[t] = p;
      Lacc += p;
    }
    __syncthreads();               // p_s visible
    // PV: thread owns e = tid; enc tile re-used from LDS
    {
      float s0 = 0.f, s1 = 0.f, s2 = 0.f, s3 = 0.f;
      const __bf16* rp = &rm[cur][tid];
      #pragma unroll
      for (int t = 0; t < 32; t += 4){
        s0 += p_s[t  ] * (float)rp[(t  )*RMW];
        s1 += p_s[t+1] * (float)rp[(t+1)*RMW];
        s2 += p_s[t+2] * (float)rp[(t+2)*RMW];
        s3 += p_s[t+3] * (float)rp[(t+3)*RMW];
      }
      cacc += (s0+s1)+(s2+s3);
    }
    __syncthreads();               // PV reads of rm[cur] done before next overwrite
  }

  partC[((size_t)th*128 + b)*512 + tid] = cacc;
  if (tid < 32){
    float Ls = Lacc;
    Ls += __shfl_xor(Ls, 1, 32);
    Ls += __shfl_xor(Ls, 2, 32);
    Ls += __shfl_xor(Ls, 4, 32);
    Ls += __shfl_xor(Ls, 8, 32);
    Ls += __shfl_xor(Ls, 16, 32);
    if (tid == 0) partL[th*128 + b] = Ls;
  }
}

// ---------------- combine 2 t-halves -> ctxt -> xh[:,512:1024], hc[:,1024:1536] --
__global__ void k_comb(const float* __restrict__ partC, const float* __restrict__ partL,
                       float* __restrict__ xh, float* __restrict__ hc)
{
  const int b = blockIdx.x, e = threadIdx.x;   // 512 threads
  float L = partL[b] + partL[128 + b];
  float v = (partC[(size_t)b*512 + e] + partC[(size_t)(128 + b)*512 + e]) / L;
  xh[(size_t)b*2048 + 512 + e] = v;
  hc[(size_t)b*1536 + 1024 + e] = v;
}

// ---------------- partial GEMM: Cpart[kc][128][N] = A[:,koff:koff+Kloc] @ W^T ------
__global__ __launch_bounds__(256,2) void k_gemm_part(
    const float* __restrict__ A, int lda,
    const float* __restrict__ W1, int ldw1,
    const float* __restrict__ W2, int ldw2, int ksplit,
    float* __restrict__ Cpart, int ldc, int Kloc)
{
  const int jt = blockIdx.x * 32;
  const int kc = blockIdx.y;
  const int koff = kc * Kloc;
  const int tid = threadIdx.x;
  const int w = tid >> 6, lane = tid & 63;
  const int la = lane & 15, g = lane >> 4;

  __shared__ __align__(16) __bf16 A_s[128][40];
  __shared__ __align__(16) __bf16 B_s[32][40];

  f32x4 acc[2][2];
  #pragma unroll
  for (int i = 0; i < 2; ++i)
    #pragma unroll
    for (int j = 0; j < 2; ++j) acc[i][j] = (f32x4){0.f,0.f,0.f,0.f};

  const int ar = tid >> 1, ac = (tid & 1) * 16;
  const int br = tid >> 3, bc = (tid & 7) * 4;

  for (int kl = 0; kl < Kloc; kl += 32){
    const int kk = koff + kl;
    {
      const float* p = A + (size_t)ar*lda + kk + ac;
      float4 v0 = *(const float4*)(p);
      float4 v1 = *(const float4*)(p+4);
      float4 v2 = *(const float4*)(p+8);
      float4 v3 = *(const float4*)(p+12);
      *(bf16x8*)&A_s[ar][ac]   = cvt8(v0,v1);
      *(bf16x8*)&A_s[ar][ac+8] = cvt8(v2,v3);
    }
    {
      const float* wp = (kk < ksplit)
          ? (W1 + (size_t)(jt+br)*ldw1 + kk + bc)
          : (W2 + (size_t)(jt+br)*ldw2 + (kk - ksplit) + bc);
      float4 v = *(const float4*)wp;
      bf16x4 bv;
      bv[0]=(__bf16)v.x; bv[1]=(__bf16)v.y; bv[2]=(__bf16)v.z; bv[3]=(__bf16)v.w;
      *(bf16x4*)&B_s[br][bc] = bv;
    }
    __syncthreads();
    bf16x8 a0 = *(const bf16x8*)&A_s[w*32 + la][g*8];
    bf16x8 a1 = *(const bf16x8*)&A_s[w*32 + 16 + la][g*8];
    bf16x8 b0 = *(const bf16x8*)&B_s[la][g*8];
    bf16x8 b1 = *(const bf16x8*)&B_s[16 + la][g*8];
    acc[0][0] = __builtin_amdgcn_mfma_f32_16x16x32_bf16(a0, b0, acc[0][0], 0,0,0);
    acc[0][1] = __builtin_amdgcn_mfma_f32_16x16x32_bf16(a0, b1, acc[0][1], 0,0,0);
    acc[1][0] = __builtin_amdgcn_mfma_f32_16x16x32_bf16(a1, b0, acc[1][0], 0,0,0);
    acc[1][1] = __builtin_amdgcn_mfma_f32_16x16x32_bf16(a1, b1, acc[1][1], 0,0,0);
    __syncthreads();
  }

  float* cp = Cpart + (size_t)kc*128*ldc;
  #pragma unroll
  for (int mfi = 0; mfi < 2; ++mfi)
    #pragma unroll
    for (int nf = 0; nf < 2; ++nf)
      #pragma unroll
      for (int r = 0; r < 4; ++r){
        int m = w*32 + mfi*16 + g*4 + r;
        int j = jt + nf*16 + la;
        cp[(size_t)m*ldc + j] = acc[mfi][nf][r];
      }
}

// ---------------- LSTM finisher: sum 4 partials + biases + pointwise ----------------
__global__ void k_lstm_fin(const float* __restrict__ partG, const float* __restrict__ b_ih,
                           const float* __restrict__ b_hh, const float* __restrict__ c0,
                           float* __restrict__ out, float* __restrict__ hc)
{
  const int idx = blockIdx.x*256 + threadIdx.x;   // 0..131071
  const int b = idx >> 10, h = idx & 1023;
  float gi = b_ih[h]        + b_hh[h];
  float gf = b_ih[1024 + h] + b_hh[1024 + h];
  float gg = b_ih[2048 + h] + b_hh[2048 + h];
  float go = b_ih[3072 + h] + b_hh[3072 + h];
  #pragma unroll
  for (int kc = 0; kc < 4; ++kc){
    const float* gp = partG + ((size_t)kc*128 + b)*4096;
    gi += gp[h]; gf += gp[1024 + h]; gg += gp[2048 + h]; go += gp[3072 + h];
  }
  float c1 = sigf(gf)*c0[idx] + sigf(gi)*tanh_f(gg);
  float h1 = sigf(go)*tanh_f(c1);
  out[131072 + idx] = h1;
  out[262144 + idx] = c1;
  hc[(size_t)b*1536 + h] = h1;
}

// ---------------- proj finisher: sum 4 partials + bias + tanh -> out[:131072] ------
__global__ void k_proj_fin(const float* __restrict__ partP, const float* __restrict__ b_proj,
                           float* __restrict__ out)
{
  const int idx = blockIdx.x*256 + threadIdx.x;   // 0..131071
  const int b = idx >> 10, j = idx & 1023;
  float s = b_proj[j];
  #pragma unroll
  for (int kc = 0; kc < 4; ++kc)
    s += partP[((size_t)kc*128 + b)*1024 + j];
  out[idx] = tanh_f(s);
}

extern "C" void kernel_launch(void* const* d_in, const int* in_sizes, int n_in,
                              void* d_out, int out_size, void* d_ws, size_t ws_size,
                              hipStream_t stream)
{
  const float* embed  = (const float*)d_in[0];
  const float* h0     = (const float*)d_in[1];
  const float* c0     = (const float*)d_in[2];
  const float* enc    = (const float*)d_in[3];
  const float* W_ph   = (const float*)d_in[4];
  const float* W_pe   = (const float*)d_in[5];
  const float* w_fc2  = (const float*)d_in[6];
  const float* W_ih   = (const float*)d_in[7];
  const float* W_hh   = (const float*)d_in[8];
  const float* b_ih   = (const float*)d_in[9];
  const float* b_hh   = (const float*)d_in[10];
  const float* W_proj = (const float*)d_in[11];
  const float* b_proj = (const float*)d_in[12];
  const unsigned char* mask = (const unsigned char*)d_in[13];

  float* ws     = (float*)d_ws;
  float* ph     = ws;                   //   32768
  float* xh     = ws + 32768;           //  262144 (128x2048: [embed|ctxt|h])
  float* hc     = ws + 294912;          //  196608 (128x1536: [h1|ctxt])
  float* partC  = ws + 491520;          //  131072 (2 x 128 x 512)
  float* partL  = ws + 622592;          //     256 (2 x 128)
  float* partG  = ws + 622848;          // 2097152 (4 x 128 x 4096)
  float* partP  = ws + 2720000;         //  524288 (4 x 128 x 1024)
  __bf16* wpeX  = (__bf16*)(ws + 3244288);   // 131072 bf16 (256 KB)
  float* out    = (float*)d_out;

  k_setup <<<320, 256, 0, stream>>>(W_pe, wpeX, h0, W_ph, ph, embed, xh);
  k_fused <<<dim3(2,128), 512, 0, stream>>>(enc, wpeX, ph, w_fc2, mask,
                                            partC, partL);
  k_comb  <<<128, 512, 0, stream>>>(partC, partL, xh, hc);
  k_gemm_part<<<dim3(128,4), 256, 0, stream>>>(xh, 2048, W_ih, 1024, W_hh, 1024, 1024,
                                               partG, 4096, 512);
  k_lstm_fin<<<512, 256, 0, stream>>>(partG, b_ih, b_hh, c0, out, hc);
  k_gemm_part<<<dim3(32,4), 256, 0, stream>>>(hc, 1536, W_proj, 1536, nullptr, 0, 1536,
                                              partP, 1024, 384);
  k_proj_fin<<<512, 256, 0, stream>>>(partP, b_proj, out);
}